// Round 14
// baseline (136.305 us; speedup 1.0000x reference)
//
#include <hip/hip_runtime.h>

#define NB 16
#define NC 256
#define NH 56
#define NW 56
#define NHW (NH * NW)          // 3136
#define NK 256
#define CAP 1024

// pass1 geometry: 8-row band x quarter channels per block -> 448 blocks
#define BR 8                   // compute rows per band
#define RS 10                  // staged rows (8 compute + 2 halo)
#define CS 8                   // channels per staged chunk
#define CQ 64                  // channels per block (quarter)
#define NCHUNK (CQ / CS)       // 8 chunks per block
#define CHUNK16 (CS * RS * NW / 4)        // 1120 16B-chunks per stage
#define NBAND (NH / BR)                   // 7
#define P1_BLOCKS (NB * NBAND * 4)        // 448 (56 per XCD)
#define NQ (BR * (NW / 4))                // 112 quads per band
#define MAPS (NB * NHW)                   // elements per map

// ---- sortable-float helpers -------------------------------------------------
__device__ inline unsigned int flip_f32(float f) {
    unsigned int u = __float_as_uint(f);
    return (u & 0x80000000u) ? ~u : (u | 0x80000000u);
}
__device__ inline float unflip_f32(unsigned int u) {
    u = (u & 0x80000000u) ? (u ^ 0x80000000u) : ~u;
    return __uint_as_float(u);
}

// ---- kernel 1: partial maps (R13 algorithm, internal x5 for MEASUREMENT) ----
__global__ void __launch_bounds__(256)
pass1_kernel(const float* __restrict__ f, float* __restrict__ maps) {
    __shared__ __align__(16) float buf[2][CS * RS * NW];   // 2 x 17920 B
    __shared__ float redbuf[NQ][2][12];                    // 10752 B

    int bid = blockIdx.x;
    int sb = (bid & 7) * (P1_BLOCKS / 8) + (bid >> 3);   // XCD-chunked
    int b = sb / 28;
    int rem0 = sb - b * 28;
    int band = rem0 >> 2;          // 0..6
    int chq = rem0 & 3;            // channel quarter
    int y0 = band * BR;
    int tid = threadIdx.x;
    const float* fb = f + (size_t)b * NC * NHW + (size_t)chq * CQ * NHW;

    auto stage = [&](int ci, float* dst) {
        int c0 = ci * CS;
#pragma unroll
        for (int i = 0; i < 5; ++i) {
            int k = tid + 256 * i;
            if (k < CHUNK16) {
                int ch = k / (RS * 14);            // 140 16B-chunks per channel
                int rem = k - ch * (RS * 14);
                int rl = rem / 14;                 // staged row 0..9
                int xk = rem - rl * 14;            // 16B chunk within row
                int rg = y0 - 1 + rl;
                rg = rg < 0 ? 0 : (rg > NH - 1 ? NH - 1 : rg);
                const float* src = fb + (size_t)(c0 + ch) * NHW + rg * NW + xk * 4;
                __builtin_amdgcn_global_load_lds(
                    (const __attribute__((address_space(1))) void*)src,
                    (__attribute__((address_space(3))) void*)(dst + k * 4),
                    16, 0, 0);
            }
        }
    };

    // compute geometry: tid<224 -> quad (8 rows x 14 quads) x chgroup(2)
    int chg = tid / NQ;                 // 0..1, each handles 4 ch per chunk
    int quad = tid - chg * NQ;          // 0..111
    int r = quad / 14, qx = quad - r * 14, x0 = qx * 4;
    int xl = x0 ? x0 - 1 : 0;
    int xr = (x0 + 4 < NW) ? x0 + 4 : NW - 1;

    for (int rep = 0; rep < 5; ++rep) {
        __syncthreads();               // previous rep fully done

        float n0 = 0.f, n1 = 0.f, n2 = 0.f, n3 = 0.f;
        float h0 = 0.f, h1 = 0.f, h2 = 0.f, h3 = 0.f;
        float w0 = 0.f, w1 = 0.f, w2 = 0.f, w3 = 0.f;

        stage(0, buf[0]);
        __syncthreads();                            // drains staging
        for (int ci = 0; ci < NCHUNK; ++ci) {
            if (ci + 1 < NCHUNK) stage(ci + 1, buf[(ci + 1) & 1]);
            if (tid < 2 * NQ) {
                const float* sbf = buf[ci & 1];
#pragma unroll
                for (int c = 0; c < 4; ++c) {
                    const float* Bm = sbf + (chg * 4 + c) * (RS * NW) + (r + 1) * NW;
                    float4 v = *(const float4*)(Bm + x0);
                    float  l = Bm[xl];
                    float  rr = Bm[xr];
                    float4 u = *(const float4*)(Bm + NW + x0);   // global y+1
                    float4 d = *(const float4*)(Bm - NW + x0);   // global y-1
                    n0 += v.x * v.x; n1 += v.y * v.y; n2 += v.z * v.z; n3 += v.w * v.w;
                    h0 += l * v.y;   h1 += v.x * v.z; h2 += v.y * v.w; h3 += v.z * rr;
                    w0 += u.x * d.x; w1 += u.y * d.y; w2 += u.z * d.z; w3 += u.w * d.w;
                }
            }
            __syncthreads();   // compute done + next stage landed
        }

        if (tid < 2 * NQ) {
            float* rb = redbuf[quad][chg];
            rb[0] = n0; rb[1] = n1; rb[2]  = n2; rb[3]  = n3;
            rb[4] = h0; rb[5] = h1; rb[6]  = h2; rb[7]  = h3;
            rb[8] = w0; rb[9] = w1; rb[10] = w2; rb[11] = w3;
        }
        __syncthreads();

        // maps layout: [chq][class n/h/v][B*HW]
        float* mbase = maps + (size_t)chq * 3 * MAPS;
        for (int oi = tid; oi < NQ * 12; oi += 256) {
            int q = oi / 12, comp = oi - q * 12;
            float acc = redbuf[q][0][comp] + redbuf[q][1][comp];
            int r2 = q / 14, qx2 = q - r2 * 14;
            int j = comp & 3;
            float* m = mbase + (size_t)(comp >> 2) * MAPS;   // 0:n 1:h 2:v
            m[((size_t)b * NH + y0 + r2) * NW + qx2 * 4 + j] = acc;
        }
    }
}

// ---- kernel 2: sim-finish (R13-exact) ---------------------------------------
__global__ void __launch_bounds__(256)
sim_kernel(const float* __restrict__ maps, unsigned int* __restrict__ sv) {
    int pix = blockIdx.x * 256 + threadIdx.x;
    if (pix >= NB * NHW) return;
    int b = pix / NHW, i = pix - b * NHW;

    int y = i / NW, x = i - y * NW;
    int xl = (x > 0) ? x - 1 : 0;
    int xr = (x < NW - 1) ? x + 1 : NW - 1;
    int yu = (y < NH - 1) ? y + 1 : NH - 1;
    int yd = (y > 0) ? y - 1 : 0;
    int il = y * NW + xl, ir = y * NW + xr;
    int iu = yu * NW + x, id = yd * NW + x;

    float nl = 0.f, nr = 0.f, nu = 0.f, nd = 0.f, h = 0.f, v = 0.f;
#pragma unroll
    for (int q = 0; q < 4; ++q) {
        const float* nq = maps + (size_t)(q * 3 + 0) * MAPS + (size_t)b * NHW;
        const float* hq = maps + (size_t)(q * 3 + 1) * MAPS + (size_t)b * NHW;
        const float* vq = maps + (size_t)(q * 3 + 2) * MAPS + (size_t)b * NHW;
        nl += nq[il]; nr += nq[ir]; nu += nq[iu]; nd += nq[id];
        h  += hq[i];  v  += vq[i];
    }
    float s = 0.5f * (h / (sqrtf(nl) * sqrtf(nr)) + v / (sqrtf(nu) * sqrtf(nd)));
    sv[pix] = flip_f32(s);
}

// ---- kernel 3: per-batch top-K (R13-exact) ----------------------------------
__global__ void __launch_bounds__(1024)
topk_kernel(const unsigned int* __restrict__ sv, int* __restrict__ idx_out,
            float* __restrict__ vals_out, float* __restrict__ y_out,
            float* __restrict__ x_out) {
    __shared__ unsigned int svals[NHW];
    __shared__ unsigned int hist[4096];
    __shared__ unsigned int wtot[16];
    __shared__ unsigned long long cand[CAP];
    __shared__ unsigned int sh_prefix, sh_mask;
    __shared__ int sh_above, sh_setS, sh_done, sh_cnt;

    const int b = blockIdx.x;
    const int tid = threadIdx.x;
    const int lane = tid & 63;
    const int wv = tid >> 6;
    const unsigned int* svb = sv + (size_t)b * NHW;

    for (int i = tid; i < NHW; i += 1024) svals[i] = svb[i];
    if (tid == 0) { sh_prefix = 0u; sh_mask = 0u; sh_above = 0; sh_done = 0; }

    const int shifts[3] = {20, 8, 0};
    const unsigned int wmasks[3] = {0xFFFu, 0xFFFu, 0xFFu};
    for (int st = 0; st < 3; ++st) {
        __syncthreads();
        int kneed = NK - sh_above;          // read post-barrier, pre-update
        if (sh_done) break;
        for (int i = tid; i < 4096; i += 1024) hist[i] = 0u;
        __syncthreads();
        unsigned int pfx = sh_prefix, msk = sh_mask;
        int shift = shifts[st];
        unsigned int wmask = wmasks[st];
        for (int i = tid; i < NHW; i += 1024) {
            unsigned int v = svals[i];
            if ((v & msk) == pfx) atomicAdd(&hist[(v >> shift) & wmask], 1u);
        }
        __syncthreads();
        unsigned int b0 = hist[4 * tid], b1 = hist[4 * tid + 1];
        unsigned int b2 = hist[4 * tid + 2], b3 = hist[4 * tid + 3];
        unsigned int lsum = b0 + b1 + b2 + b3;
        unsigned int s = lsum;
#pragma unroll
        for (int d = 1; d < 64; d <<= 1) {
            unsigned int t2 = __shfl_down(s, d);
            s += (lane + d < 64) ? t2 : 0u;
        }
        if (lane == 0) wtot[wv] = s;        // wave total
        __syncthreads();
        unsigned int wabove = 0;
        for (int w = wv + 1; w < 16; ++w) wabove += wtot[w];
        unsigned int thr_above = wabove + (s - lsum);   // strictly above my bins
        unsigned int suf3 = thr_above + b3;
        unsigned int suf2 = suf3 + b2;
        unsigned int suf1 = suf2 + b1;
        unsigned int suf0 = suf1 + b0;
        if (suf0 >= (unsigned int)kneed && thr_above < (unsigned int)kneed) {
            int c; unsigned int above, hc;
            if (suf3 >= (unsigned int)kneed)      { c = 4 * tid + 3; above = thr_above; hc = b3; }
            else if (suf2 >= (unsigned int)kneed) { c = 4 * tid + 2; above = suf3;      hc = b2; }
            else if (suf1 >= (unsigned int)kneed) { c = 4 * tid + 1; above = suf2;      hc = b1; }
            else                                  { c = 4 * tid + 0; above = suf1;      hc = b0; }
            sh_above += (int)above;
            sh_setS = (int)hc;
            sh_prefix = pfx | ((unsigned int)c << shift);
            sh_mask = msk | (wmask << shift);
            if (sh_above + sh_setS <= CAP || st == 2) sh_done = 1;
        }
    }
    __syncthreads();

    if (tid == 0) sh_cnt = 0;
    __syncthreads();
    unsigned int T = sh_prefix;
    for (int i = tid; i < NHW; i += 1024) {
        unsigned int v = svals[i];
        bool keep = (v >= T);
        unsigned long long m = __ballot(keep);
        int basep = 0;
        if (lane == 0) basep = atomicAdd(&sh_cnt, __popcll(m));
        basep = __shfl(basep, 0);
        if (keep) {
            int pos = basep + __popcll(m & ((1ull << lane) - 1ull));
            if (pos < CAP)
                cand[pos] = ((unsigned long long)v << 32) |
                            (unsigned long long)(0xFFFFFFFFu - (unsigned int)i);
        }
    }
    __syncthreads();
    int nc = sh_cnt; if (nc > CAP) nc = CAP;

    if (tid < nc) {
        unsigned long long my = cand[tid];
        int rank = 0;
        for (int i = 0; i < nc; ++i) rank += (cand[i] > my);
        if (rank < NK) {
            unsigned int lo = (unsigned int)(my & 0xFFFFFFFFull);
            int idx = (int)(0xFFFFFFFFu - lo);
            float val = unflip_f32((unsigned int)(my >> 32));
            int o = b * NK + rank;
            idx_out[o] = idx;
            vals_out[o] = val;
            y_out[o] = (float)(idx / NW);
            x_out[o] = (float)(idx % NW);
        }
    }
}

// ---- kernel 4: gather (R13 algorithm, rotated-tile x8 for MEASUREMENT) ------
// Rep r processes channel tile ((bid&31)+4r)&31 -> every rep touches DIFFERENT
// 64B lines (cold measurement; defeats the L1-warm-rep artifact of R11).
// Each tile written 8x by different blocks with identical values -> benign,
// deterministic. gather_cold = dispatch_dur / 8.
#define GCT 8
__global__ void __launch_bounds__(256)
gather_kernel(const float* __restrict__ f, const int* __restrict__ idx,
              float* __restrict__ out) {
    int bid = blockIdx.x;              // 512 = 16 b x 32 ctiles
    int b = bid >> 5;
    int t = threadIdx.x;               // point rank k
    int p = idx[b * NK + t];
    const float* fB = f + (size_t)b * NC * NHW;
    float* oB = out + ((size_t)b * NK + t) * NC;

    for (int rep = 0; rep < 8; ++rep) {
        int c0 = (((bid & 31) + 4 * rep) & 31) * GCT;
        const float* fb = fB + (size_t)c0 * NHW;
        float v[GCT];
#pragma unroll
        for (int ci = 0; ci < GCT; ++ci) v[ci] = fb[(size_t)ci * NHW + p];
        float4 a = make_float4(v[0], v[1], v[2], v[3]);
        float4 b4 = make_float4(v[4], v[5], v[6], v[7]);
        *(float4*)(oB + c0) = a;
        *(float4*)(oB + c0 + 4) = b4;
        __asm__ __volatile__("" ::: "memory");
    }
}

extern "C" void kernel_launch(void* const* d_in, const int* in_sizes, int n_in,
                              void* d_out, int out_size, void* d_ws, size_t ws_size,
                              hipStream_t stream) {
    const float* f = (const float*)d_in[0];

    // output layout: point_feat [B,K,C] | vals [B,K] | ycoord [B,K] | xcoord [B,K]
    float* out_feat = (float*)d_out;
    float* out_vals = out_feat + (size_t)NB * NK * NC;
    float* out_y    = out_vals + (size_t)NB * NK;
    float* out_x    = out_y    + (size_t)NB * NK;

    // workspace: 12 partial maps (n,h,v x 4 quarters) | svals map | idx
    float* maps = (float*)d_ws;
    unsigned int* sv = (unsigned int*)(maps + 12 * (size_t)MAPS);
    int* idx = (int*)(sv + MAPS);

    pass1_kernel<<<P1_BLOCKS, 256, 0, stream>>>(f, maps);
    sim_kernel<<<(NB * NHW + 255) / 256, 256, 0, stream>>>(maps, sv);
    topk_kernel<<<NB, 1024, 0, stream>>>(sv, idx, out_vals, out_y, out_x);
    gather_kernel<<<NB * (NC / GCT), 256, 0, stream>>>(f, idx, out_feat);
}

// Round 15
// 38.839 us; speedup vs baseline: 3.5095x; 3.5095x over previous
//
#include <hip/hip_runtime.h>

#define NB 16
#define NC 256
#define NH 56
#define NW 56
#define NHW (NH * NW)          // 3136
#define NK 256
#define CAP 1024

// pass1 geometry: 8-row band x quarter channels per block -> 448 blocks
#define BR 8                   // compute rows per band
#define RS 10                  // staged rows (8 compute + 2 halo)
#define CS 8                   // channels per staged chunk
#define CQ 64                  // channels per block (quarter)
#define NCHUNK (CQ / CS)       // 8 chunks per block
#define CHUNK16 (CS * RS * NW / 4)        // 1120 16B-chunks per stage
#define NBAND (NH / BR)                   // 7
#define P1_BLOCKS (NB * NBAND * 4)        // 448 (56 per XCD)
#define NQ (BR * (NW / 4))                // 112 quads per band
#define MAPS (NB * NHW)                   // elements per map

// gather geometry: 112-pixel tile x 64-channel chunks
#define GPX 112                // pixels per tile
#define GNT (NHW / GPX)        // 28 tiles
#define GCC 64                 // channels per chunk
#define GCH16 (GCC * GPX * 4 / 16)        // 1792 16B-chunks per stage (7x256)

// ---- sortable-float helpers -------------------------------------------------
__device__ inline unsigned int flip_f32(float f) {
    unsigned int u = __float_as_uint(f);
    return (u & 0x80000000u) ? ~u : (u | 0x80000000u);
}
__device__ inline float unflip_f32(unsigned int u) {
    u = (u & 0x80000000u) ? (u ^ 0x80000000u) : ~u;
    return __uint_as_float(u);
}

// ---- kernel 1: partial norm2 / hprod / vprod maps (R13-exact) ---------------
__global__ void __launch_bounds__(256)
pass1_kernel(const float* __restrict__ f, float* __restrict__ maps) {
    __shared__ __align__(16) float buf[2][CS * RS * NW];   // 2 x 17920 B
    __shared__ float redbuf[NQ][2][12];                    // 10752 B

    int bid = blockIdx.x;
    int sb = (bid & 7) * (P1_BLOCKS / 8) + (bid >> 3);   // XCD-chunked
    int b = sb / 28;
    int rem0 = sb - b * 28;
    int band = rem0 >> 2;          // 0..6
    int chq = rem0 & 3;            // channel quarter
    int y0 = band * BR;
    int tid = threadIdx.x;
    const float* fb = f + (size_t)b * NC * NHW + (size_t)chq * CQ * NHW;

    auto stage = [&](int ci, float* dst) {
        int c0 = ci * CS;
#pragma unroll
        for (int i = 0; i < 5; ++i) {
            int k = tid + 256 * i;
            if (k < CHUNK16) {
                int ch = k / (RS * 14);            // 140 16B-chunks per channel
                int rem = k - ch * (RS * 14);
                int rl = rem / 14;                 // staged row 0..9
                int xk = rem - rl * 14;            // 16B chunk within row
                int rg = y0 - 1 + rl;
                rg = rg < 0 ? 0 : (rg > NH - 1 ? NH - 1 : rg);
                const float* src = fb + (size_t)(c0 + ch) * NHW + rg * NW + xk * 4;
                __builtin_amdgcn_global_load_lds(
                    (const __attribute__((address_space(1))) void*)src,
                    (__attribute__((address_space(3))) void*)(dst + k * 4),
                    16, 0, 0);
            }
        }
    };

    // compute geometry: tid<224 -> quad (8 rows x 14 quads) x chgroup(2)
    int chg = tid / NQ;                 // 0..1, each handles 4 ch per chunk
    int quad = tid - chg * NQ;          // 0..111
    int r = quad / 14, qx = quad - r * 14, x0 = qx * 4;
    int xl = x0 ? x0 - 1 : 0;
    int xr = (x0 + 4 < NW) ? x0 + 4 : NW - 1;

    float n0 = 0.f, n1 = 0.f, n2 = 0.f, n3 = 0.f;
    float h0 = 0.f, h1 = 0.f, h2 = 0.f, h3 = 0.f;
    float w0 = 0.f, w1 = 0.f, w2 = 0.f, w3 = 0.f;

    stage(0, buf[0]);
    __syncthreads();                            // drains staging
    for (int ci = 0; ci < NCHUNK; ++ci) {
        if (ci + 1 < NCHUNK) stage(ci + 1, buf[(ci + 1) & 1]);
        if (tid < 2 * NQ) {
            const float* sbf = buf[ci & 1];
#pragma unroll
            for (int c = 0; c < 4; ++c) {
                const float* Bm = sbf + (chg * 4 + c) * (RS * NW) + (r + 1) * NW;
                float4 v = *(const float4*)(Bm + x0);
                float  l = Bm[xl];
                float  rr = Bm[xr];
                float4 u = *(const float4*)(Bm + NW + x0);   // global y+1
                float4 d = *(const float4*)(Bm - NW + x0);   // global y-1
                n0 += v.x * v.x; n1 += v.y * v.y; n2 += v.z * v.z; n3 += v.w * v.w;
                h0 += l * v.y;   h1 += v.x * v.z; h2 += v.y * v.w; h3 += v.z * rr;
                w0 += u.x * d.x; w1 += u.y * d.y; w2 += u.z * d.z; w3 += u.w * d.w;
            }
        }
        __syncthreads();   // compute done + next stage landed
    }

    if (tid < 2 * NQ) {
        float* rb = redbuf[quad][chg];
        rb[0] = n0; rb[1] = n1; rb[2]  = n2; rb[3]  = n3;
        rb[4] = h0; rb[5] = h1; rb[6]  = h2; rb[7]  = h3;
        rb[8] = w0; rb[9] = w1; rb[10] = w2; rb[11] = w3;
    }
    __syncthreads();

    // maps layout: [chq][class n/h/v][B*HW]
    float* mbase = maps + (size_t)chq * 3 * MAPS;
    for (int oi = tid; oi < NQ * 12; oi += 256) {
        int q = oi / 12, comp = oi - q * 12;
        float acc = redbuf[q][0][comp] + redbuf[q][1][comp];
        int r2 = q / 14, qx2 = q - r2 * 14;
        int j = comp & 3;
        float* m = mbase + (size_t)(comp >> 2) * MAPS;   // 0:n 1:h 2:v
        m[((size_t)b * NH + y0 + r2) * NW + qx2 * 4 + j] = acc;
    }
}

// ---- kernel 2: sim-finish (R13-exact) ---------------------------------------
__global__ void __launch_bounds__(256)
sim_kernel(const float* __restrict__ maps, unsigned int* __restrict__ sv) {
    int pix = blockIdx.x * 256 + threadIdx.x;
    if (pix >= NB * NHW) return;
    int b = pix / NHW, i = pix - b * NHW;

    int y = i / NW, x = i - y * NW;
    int xl = (x > 0) ? x - 1 : 0;
    int xr = (x < NW - 1) ? x + 1 : NW - 1;
    int yu = (y < NH - 1) ? y + 1 : NH - 1;
    int yd = (y > 0) ? y - 1 : 0;
    int il = y * NW + xl, ir = y * NW + xr;
    int iu = yu * NW + x, id = yd * NW + x;

    float nl = 0.f, nr = 0.f, nu = 0.f, nd = 0.f, h = 0.f, v = 0.f;
#pragma unroll
    for (int q = 0; q < 4; ++q) {
        const float* nq = maps + (size_t)(q * 3 + 0) * MAPS + (size_t)b * NHW;
        const float* hq = maps + (size_t)(q * 3 + 1) * MAPS + (size_t)b * NHW;
        const float* vq = maps + (size_t)(q * 3 + 2) * MAPS + (size_t)b * NHW;
        nl += nq[il]; nr += nq[ir]; nu += nq[iu]; nd += nq[id];
        h  += hq[i];  v  += vq[i];
    }
    float s = 0.5f * (h / (sqrtf(nl) * sqrtf(nr)) + v / (sqrtf(nu) * sqrtf(nd)));
    sv[pix] = flip_f32(s);
}

// ---- kernel 3: per-batch top-K (R13-exact) ----------------------------------
__global__ void __launch_bounds__(1024)
topk_kernel(const unsigned int* __restrict__ sv, int* __restrict__ idx_out,
            float* __restrict__ vals_out, float* __restrict__ y_out,
            float* __restrict__ x_out) {
    __shared__ unsigned int svals[NHW];
    __shared__ unsigned int hist[4096];
    __shared__ unsigned int wtot[16];
    __shared__ unsigned long long cand[CAP];
    __shared__ unsigned int sh_prefix, sh_mask;
    __shared__ int sh_above, sh_setS, sh_done, sh_cnt;

    const int b = blockIdx.x;
    const int tid = threadIdx.x;
    const int lane = tid & 63;
    const int wv = tid >> 6;
    const unsigned int* svb = sv + (size_t)b * NHW;

    for (int i = tid; i < NHW; i += 1024) svals[i] = svb[i];
    if (tid == 0) { sh_prefix = 0u; sh_mask = 0u; sh_above = 0; sh_done = 0; }

    const int shifts[3] = {20, 8, 0};
    const unsigned int wmasks[3] = {0xFFFu, 0xFFFu, 0xFFu};
    for (int st = 0; st < 3; ++st) {
        __syncthreads();
        int kneed = NK - sh_above;          // read post-barrier, pre-update
        if (sh_done) break;
        for (int i = tid; i < 4096; i += 1024) hist[i] = 0u;
        __syncthreads();
        unsigned int pfx = sh_prefix, msk = sh_mask;
        int shift = shifts[st];
        unsigned int wmask = wmasks[st];
        for (int i = tid; i < NHW; i += 1024) {
            unsigned int v = svals[i];
            if ((v & msk) == pfx) atomicAdd(&hist[(v >> shift) & wmask], 1u);
        }
        __syncthreads();
        unsigned int b0 = hist[4 * tid], b1 = hist[4 * tid + 1];
        unsigned int b2 = hist[4 * tid + 2], b3 = hist[4 * tid + 3];
        unsigned int lsum = b0 + b1 + b2 + b3;
        unsigned int s = lsum;
#pragma unroll
        for (int d = 1; d < 64; d <<= 1) {
            unsigned int t2 = __shfl_down(s, d);
            s += (lane + d < 64) ? t2 : 0u;
        }
        if (lane == 0) wtot[wv] = s;        // wave total
        __syncthreads();
        unsigned int wabove = 0;
        for (int w = wv + 1; w < 16; ++w) wabove += wtot[w];
        unsigned int thr_above = wabove + (s - lsum);   // strictly above my bins
        unsigned int suf3 = thr_above + b3;
        unsigned int suf2 = suf3 + b2;
        unsigned int suf1 = suf2 + b1;
        unsigned int suf0 = suf1 + b0;
        if (suf0 >= (unsigned int)kneed && thr_above < (unsigned int)kneed) {
            int c; unsigned int above, hc;
            if (suf3 >= (unsigned int)kneed)      { c = 4 * tid + 3; above = thr_above; hc = b3; }
            else if (suf2 >= (unsigned int)kneed) { c = 4 * tid + 2; above = suf3;      hc = b2; }
            else if (suf1 >= (unsigned int)kneed) { c = 4 * tid + 1; above = suf2;      hc = b1; }
            else                                  { c = 4 * tid + 0; above = suf1;      hc = b0; }
            sh_above += (int)above;
            sh_setS = (int)hc;
            sh_prefix = pfx | ((unsigned int)c << shift);
            sh_mask = msk | (wmask << shift);
            if (sh_above + sh_setS <= CAP || st == 2) sh_done = 1;
        }
    }
    __syncthreads();

    if (tid == 0) sh_cnt = 0;
    __syncthreads();
    unsigned int T = sh_prefix;
    for (int i = tid; i < NHW; i += 1024) {
        unsigned int v = svals[i];
        bool keep = (v >= T);
        unsigned long long m = __ballot(keep);
        int basep = 0;
        if (lane == 0) basep = atomicAdd(&sh_cnt, __popcll(m));
        basep = __shfl(basep, 0);
        if (keep) {
            int pos = basep + __popcll(m & ((1ull << lane) - 1ull));
            if (pos < CAP)
                cand[pos] = ((unsigned long long)v << 32) |
                            (unsigned long long)(0xFFFFFFFFu - (unsigned int)i);
        }
    }
    __syncthreads();
    int nc = sh_cnt; if (nc > CAP) nc = CAP;

    if (tid < nc) {
        unsigned long long my = cand[tid];
        int rank = 0;
        for (int i = 0; i < nc; ++i) rank += (cand[i] > my);
        if (rank < NK) {
            unsigned int lo = (unsigned int)(my & 0xFFFFFFFFull);
            int idx = (int)(0xFFFFFFFFu - lo);
            float val = unflip_f32((unsigned int)(my >> 32));
            int o = b * NK + rank;
            idx_out[o] = idx;
            vals_out[o] = val;
            y_out[o] = (float)(idx / NW);
            x_out[o] = (float)(idx % NW);
        }
    }
}

// ---- kernel 4: gather via dense stream + LDS pick ---------------------------
// Block = (batch, 112-pixel tile). Streams its pixel range for ALL 256
// channels in four 64-ch chunks (28 KB, double-buffered) via global_load_lds
// -> fully coalesced 448B-per-channel runs (51 MB total, L3-warm). The ~9
// points whose p falls in the tile pick from LDS and write 256B contiguous
// output runs. Replaces the scattered-line gather that was stuck at ~3 TB/s
// service rate (R14 measurement: 10 us, 29.5 MB at 0.5% VALUBusy).
__global__ void __launch_bounds__(256)
gather_kernel(const float* __restrict__ f, const int* __restrict__ idx,
              float* __restrict__ out) {
    __shared__ __align__(16) float buf[2][GCC * GPX];   // 2 x 28672 B

    int bid = blockIdx.x;              // 448 = 16 b x 28 tiles
    int b = bid / GNT;
    int p0 = (bid - b * GNT) * GPX;
    int tid = threadIdx.x;
    const float* fB = f + (size_t)b * NC * NHW;

    // my point (thread t owns point rank t)
    int p = idx[b * NK + tid];
    int o = p - p0;
    bool mine = (o >= 0) && (o < GPX);
    float* outp = out + ((size_t)b * NK + tid) * NC;

    auto stage = [&](int ci, float* dst) {
        int c0 = ci * GCC;
#pragma unroll
        for (int i = 0; i < 7; ++i) {
            int k = tid + 256 * i;                 // 1792 = 7*256 exactly
            int ch = k / (GPX / 4);                // 28 16B-chunks per channel
            int xk = k - ch * (GPX / 4);
            const float* src = fB + (size_t)(c0 + ch) * NHW + p0 + xk * 4;
            __builtin_amdgcn_global_load_lds(
                (const __attribute__((address_space(1))) void*)src,
                (__attribute__((address_space(3))) void*)(dst + k * 4),
                16, 0, 0);
        }
    };

    stage(0, buf[0]);
    __syncthreads();                               // staging drained
    for (int ci = 0; ci < 4; ++ci) {
        if (ci + 1 < 4) stage(ci + 1, buf[(ci + 1) & 1]);
        if (mine) {
            const float* sbf = buf[ci & 1];
            float* op = outp + ci * GCC;
#pragma unroll
            for (int g = 0; g < GCC / 4; ++g) {
                float4 w;
                w.x = sbf[(4 * g + 0) * GPX + o];
                w.y = sbf[(4 * g + 1) * GPX + o];
                w.z = sbf[(4 * g + 2) * GPX + o];
                w.w = sbf[(4 * g + 3) * GPX + o];
                *(float4*)(op + 4 * g) = w;
            }
        }
        __syncthreads();                           // picks done + next stage landed
    }
}

extern "C" void kernel_launch(void* const* d_in, const int* in_sizes, int n_in,
                              void* d_out, int out_size, void* d_ws, size_t ws_size,
                              hipStream_t stream) {
    const float* f = (const float*)d_in[0];

    // output layout: point_feat [B,K,C] | vals [B,K] | ycoord [B,K] | xcoord [B,K]
    float* out_feat = (float*)d_out;
    float* out_vals = out_feat + (size_t)NB * NK * NC;
    float* out_y    = out_vals + (size_t)NB * NK;
    float* out_x    = out_y    + (size_t)NB * NK;

    // workspace: 12 partial maps (n,h,v x 4 quarters) | svals map | idx
    float* maps = (float*)d_ws;
    unsigned int* sv = (unsigned int*)(maps + 12 * (size_t)MAPS);
    int* idx = (int*)(sv + MAPS);

    pass1_kernel<<<P1_BLOCKS, 256, 0, stream>>>(f, maps);
    sim_kernel<<<(NB * NHW + 255) / 256, 256, 0, stream>>>(maps, sv);
    topk_kernel<<<NB, 1024, 0, stream>>>(sv, idx, out_vals, out_y, out_x);
    gather_kernel<<<NB * GNT, 256, 0, stream>>>(f, idx, out_feat);
}